// Round 3
// baseline (1082.875 us; speedup 1.0000x reference)
//
#include <hip/hip_runtime.h>
#include <hip/hip_bf16.h>
#include <math.h>

#define GAMMA 0.1f
#define EPSILON 0.1f
#define NUM_ITERS 4

typedef __attribute__((ext_vector_type(8))) short short8;   // 8 bf16 bit-patterns
typedef __attribute__((ext_vector_type(4))) float floatx4;

__device__ __forceinline__ float bf2f(unsigned short u) {
  union { unsigned int i; float f; } v; v.i = ((unsigned int)u) << 16; return v.f;
}
__device__ __forceinline__ unsigned short f2bf(float f) {
  union { float f; unsigned int i; } v; v.f = f;
  unsigned int x = v.i;
  return (unsigned short)((x + 0x7fffu + ((x >> 16) & 1u)) >> 16);
}
__device__ __forceinline__ unsigned int f2_to_bfx2(float a, float b) {
  return (unsigned int)f2bf(a) | (((unsigned int)f2bf(b)) << 16);
}
__device__ __forceinline__ float2 bfx2_to_f2(unsigned int u) {
  union { unsigned int i; float f; } lo, hi;
  lo.i = u << 16; hi.i = u & 0xffff0000u;
  return make_float2(lo.f, hi.f);
}

// ------------------------------------------------------------- dtype detect

// flag=1 if x is float32, 0 if bf16. Low 16 bits of random fp32 are mantissa
// noise -> as bf16 ~47% have |v|>64 or NaN; true bf16 N(0,1) never does.
__global__ void detect_kernel(const unsigned int* __restrict__ x, int* __restrict__ flag) {
  __shared__ int ws4[4];
  int tid = threadIdx.x;
  int bad = 0;
  for (int i = tid; i < 2048; i += 256) {
    unsigned int u = x[i];
    float lo = bf2f((unsigned short)(u & 0xffffu));
    if (!(fabsf(lo) <= 64.0f)) bad++;   // also true for NaN
  }
#pragma unroll
  for (int d = 1; d < 64; d <<= 1) bad += __shfl_xor(bad, d, 64);
  if ((tid & 63) == 0) ws4[tid >> 6] = bad;
  __syncthreads();
  if (tid == 0) *flag = (ws4[0] + ws4[1] + ws4[2] + ws4[3] > 64) ? 1 : 0;
}

// ------------------------------------------------------------- setup

__global__ void fill_kernel(unsigned short* __restrict__ out, int n, unsigned short val) {
  int t = blockIdx.x * blockDim.x + threadIdx.x;
  if (t < n) out[t] = val;
}

// Am = bf16(W - W^T - gamma*I); Wb = bf16(Wphi); bias_f = f32(bias)
__global__ void prep_kernel(const void* __restrict__ Wv, const void* __restrict__ Wphiv,
                            const void* __restrict__ biasv, const int* __restrict__ flag,
                            unsigned short* __restrict__ Am, unsigned short* __restrict__ Wb,
                            float* __restrict__ bias_f) {
  int t = blockIdx.x * blockDim.x + threadIdx.x;
  if (t >= 128 * 128) return;
  int isf = *flag;
  int j = t >> 7, k = t & 127;
  float w_jk, w_kj, wp;
  if (isf) {
    const float* W = (const float*)Wv;
    const float* Wp = (const float*)Wphiv;
    w_jk = W[t]; w_kj = W[k * 128 + j]; wp = Wp[t];
  } else {
    const unsigned short* W = (const unsigned short*)Wv;
    const unsigned short* Wp = (const unsigned short*)Wphiv;
    w_jk = bf2f(W[t]); w_kj = bf2f(W[k * 128 + j]); wp = bf2f(Wp[t]);
  }
  float v = w_jk - w_kj;
  if (j == k) v -= GAMMA;
  Am[t] = f2bf(v);
  Wb[t] = f2bf(wp);
  if (t < 128)
    bias_f[t] = isf ? ((const float*)biasv)[t] : bf2f(((const unsigned short*)biasv)[t]);
}

// xf32 <- f32(x_in), pad rows zero. One thread per 4 elements.
__global__ void init_x_kernel(const void* __restrict__ xinv, const int* __restrict__ flag,
                              float* __restrict__ xf32, int N, int NP) {
  int t = blockIdx.x * blockDim.x + threadIdx.x;
  if (t >= NP * 32) return;
  int base = t * 4;
  int row = base >> 7;
  float4 o;
  if (row < N) {
    if (*flag) {
      o = *(const float4*)((const float*)xinv + base);
    } else {
      uint2 v = *(const uint2*)((const unsigned short*)xinv + base);
      float2 f0 = bfx2_to_f2(v.x), f1 = bfx2_to_f2(v.y);
      o = make_float4(f0.x, f0.y, f1.x, f1.y);
    }
  } else {
    o = make_float4(0.f, 0.f, 0.f, 0.f);
  }
  *(float4*)(xf32 + base) = o;
}

__global__ void hist_kernel(const int* __restrict__ dst, int* __restrict__ deg, int E) {
  int t = blockIdx.x * blockDim.x + threadIdx.x;
  if (t < E) atomicAdd(&deg[dst[t]], 1);
}

__global__ void dinv_kernel(const int* __restrict__ deg, float* __restrict__ dinv,
                            int N, int NP) {
  int t = blockIdx.x * blockDim.x + threadIdx.x;
  if (t >= NP) return;
  dinv[t] = (t < N) ? rsqrtf((float)deg[t] + 1.0f) : 1.0f;
}

// -------- 3-kernel exclusive scan of deg -> offs (+ cursor), 1024 elems/block

__global__ void scan_bsum_kernel(const int* __restrict__ counts, int* __restrict__ bsum, int n) {
  __shared__ int wsh[4];
  int tid = threadIdx.x;
  int i0 = blockIdx.x * 1024 + tid * 4;
  int s = 0;
#pragma unroll
  for (int k = 0; k < 4; ++k) { int i = i0 + k; if (i < n) s += counts[i]; }
#pragma unroll
  for (int d = 1; d < 64; d <<= 1) s += __shfl_xor(s, d, 64);
  if ((tid & 63) == 0) wsh[tid >> 6] = s;
  __syncthreads();
  if (tid == 0) bsum[blockIdx.x] = wsh[0] + wsh[1] + wsh[2] + wsh[3];
}

__global__ void scan_partials_kernel(int* __restrict__ bsum, int nb) {
  if (threadIdx.x == 0 && blockIdx.x == 0) {
    int run = 0;
    for (int i = 0; i < nb; ++i) { int v = bsum[i]; bsum[i] = run; run += v; }
  }
}

__global__ void scan_final_kernel(const int* __restrict__ counts, const int* __restrict__ bsum,
                                  int* __restrict__ offs, int* __restrict__ cursor,
                                  int n, int total) {
  __shared__ int wsh[4];
  int tid = threadIdx.x, lane = tid & 63, wid = tid >> 6;
  int i0 = blockIdx.x * 1024 + tid * 4;
  int v[4]; int s = 0;
#pragma unroll
  for (int k = 0; k < 4; ++k) { int i = i0 + k; v[k] = (i < n) ? counts[i] : 0; s += v[k]; }
  int incl = s;
#pragma unroll
  for (int d = 1; d < 64; d <<= 1) { int t2 = __shfl_up(incl, d, 64); if (lane >= d) incl += t2; }
  if (lane == 63) wsh[wid] = incl;
  __syncthreads();
  int wexcl = 0;
  for (int k = 0; k < wid; ++k) wexcl += wsh[k];
  int run = bsum[blockIdx.x] + wexcl + (incl - s);
#pragma unroll
  for (int k = 0; k < 4; ++k) {
    int i = i0 + k;
    if (i < n) { offs[i] = run; cursor[i] = run; }
    run += v[k];
  }
  if (blockIdx.x == 0 && tid == 0) offs[n] = total;
}

__global__ void scatter_kernel(const int* __restrict__ src, const int* __restrict__ dst,
                               int* __restrict__ cursor, int* __restrict__ csr_src, int E) {
  int t = blockIdx.x * blockDim.x + threadIdx.x;
  if (t >= E) return;
  int pos = atomicAdd(&cursor[dst[t]], 1);
  csr_src[pos] = src[t];
}

// ------------------------------------------------------------- per-iteration

// 64-row tile, K=128. A staged from f32 state (cvt->bf16), B (bf16) from ws.
// mode 0: y[row,:] = bf16( (x@B^T)[row,:] * dinv[row] )
// mode 1: s = x@B^T + g + bias; h = tanh(s); xstate += eps*h;
//         if (outb) write xstate' as f32 (flag) or bf16.
__global__ __launch_bounds__(256) void gemm_kernel(
    const float* __restrict__ xf32,
    const unsigned short* __restrict__ Bmat,   // [128][128] bf16 row-major [n][k]
    const float* __restrict__ dinv,
    const unsigned short* __restrict__ g,
    const float* __restrict__ bias_f,
    float* __restrict__ xstate,
    void* __restrict__ outb,
    const int* __restrict__ flag,
    int mode, int Mvalid) {
  __shared__ unsigned short xs[64 * 128];    // 16 KB
  __shared__ unsigned short bs[128 * 128];   // 32 KB
  const int tid = threadIdx.x;
  const int lane = tid & 63;
  const int wid = tid >> 6;
  const int m0 = blockIdx.x * 64;

  // stage A: thread t covers row r=t>>2, cols q*32..q*32+31 (f32 -> bf16)
  {
    int r = tid >> 2, q = tid & 3;
    const float* srcp = xf32 + (size_t)(m0 + r) * 128 + q * 32;
    unsigned short* dstp = xs + r * 128 + q * 32;
#pragma unroll
    for (int k = 0; k < 8; ++k) {
      float4 f = *(const float4*)(srcp + k * 4);
      *(uint2*)(dstp + k * 4) = make_uint2(f2_to_bfx2(f.x, f.y), f2_to_bfx2(f.z, f.w));
    }
  }
  // stage B: thread t covers row r=t>>1, cols h*64..h*64+63
  {
    int r = tid >> 1, h = tid & 1;
    const unsigned short* srcp = Bmat + r * 128 + h * 64;
    unsigned short* dstp = bs + r * 128 + h * 64;
#pragma unroll
    for (int k = 0; k < 8; ++k)
      *(uint4*)(dstp + k * 8) = *(const uint4*)(srcp + k * 8);
  }
  __syncthreads();

  const int l15 = lane & 15;
  const int quad = lane >> 4;

  floatx4 acc[8];
  const floatx4 zero = {0.f, 0.f, 0.f, 0.f};
#pragma unroll
  for (int j = 0; j < 8; ++j) acc[j] = zero;

#pragma unroll
  for (int kk = 0; kk < 4; ++kk) {
    const int koff = kk * 32 + quad * 8;
    short8 a = *(const short8*)&xs[(wid * 16 + l15) * 128 + koff];
#pragma unroll
    for (int j = 0; j < 8; ++j) {
      short8 b = *(const short8*)&bs[(j * 16 + l15) * 128 + koff];
      acc[j] = __builtin_amdgcn_mfma_f32_16x16x32_bf16(a, b, acc[j], 0, 0, 0);
    }
  }

  // C/D layout (m89-verified): col = lane&15, row = (lane>>4)*4 + reg
  if (mode == 0) {
#pragma unroll
    for (int r = 0; r < 4; ++r) {
      int row = m0 + wid * 16 + quad * 4 + r;
      float dv = dinv[row];
#pragma unroll
      for (int j = 0; j < 8; ++j)
        ((unsigned short*)outb)[(size_t)row * 128 + j * 16 + l15] = f2bf(acc[j][r] * dv);
    }
  } else {
    int isf = flag ? *flag : 0;
#pragma unroll
    for (int r = 0; r < 4; ++r) {
      int row = m0 + wid * 16 + quad * 4 + r;
      if (row < Mvalid) {
#pragma unroll
        for (int j = 0; j < 8; ++j) {
          int col = j * 16 + l15;
          size_t idx = (size_t)row * 128 + col;
          float s = acc[j][r] + bf2f(g[idx]) + bias_f[col];
          float h = tanhf(s);
          float xn = xstate[idx] + EPSILON * h;
          xstate[idx] = xn;
          if (outb) {
            if (isf) ((float*)outb)[idx] = xn;
            else     ((unsigned short*)outb)[idx] = f2bf(xn);
          }
        }
      }
    }
  }
}

// one wave per node: g[i] = bf16( dinv[i] * ( sum_{e in(i)} y[src_e] + y[i] ) )
__global__ __launch_bounds__(256) void agg_kernel(
    const unsigned short* __restrict__ y,
    const int* __restrict__ offs,
    const int* __restrict__ csr_src,
    const float* __restrict__ dinv,
    unsigned short* __restrict__ g,
    int N) {
  int i = blockIdx.x * 4 + (threadIdx.x >> 6);
  if (i >= N) return;
  int lane = threadIdx.x & 63;
  int c2 = lane * 2;

  float2 acc = bfx2_to_f2(*(const unsigned int*)(y + (size_t)i * 128 + c2));  // self

  int e0 = offs[i], e1 = offs[i + 1];
  int e = e0;
  for (; e + 2 <= e1; e += 2) {
    int s0 = csr_src[e], s1 = csr_src[e + 1];
    float2 f0 = bfx2_to_f2(*(const unsigned int*)(y + (size_t)s0 * 128 + c2));
    float2 f1 = bfx2_to_f2(*(const unsigned int*)(y + (size_t)s1 * 128 + c2));
    acc.x += f0.x + f1.x;
    acc.y += f0.y + f1.y;
  }
  if (e < e1) {
    int s0 = csr_src[e];
    float2 f0 = bfx2_to_f2(*(const unsigned int*)(y + (size_t)s0 * 128 + c2));
    acc.x += f0.x;
    acc.y += f0.y;
  }
  float dv = dinv[i];
  *(unsigned int*)(g + (size_t)i * 128 + c2) = f2_to_bfx2(acc.x * dv, acc.y * dv);
}

// ------------------------------------------------------------- launch

extern "C" void kernel_launch(void* const* d_in, const int* in_sizes, int n_in,
                              void* d_out, int out_size, void* d_ws, size_t ws_size,
                              hipStream_t stream) {
  const void* x_in = d_in[0];
  const int* ei = (const int*)d_in[1];
  const void* W = d_in[2];
  const void* Wphi = d_in[3];
  const void* bias = d_in[4];

  const int N = in_sizes[0] / 128;
  const int E = in_sizes[1] / 2;
  const int NP = ((N + 63) / 64) * 64;
  const int* src = ei;
  const int* dst = ei + E;
  const int nb = (N + 1023) / 1024;

  // workspace layout
  size_t off = 0;
  auto place = [&](size_t bytes) { size_t r = off; off = (off + bytes + 255) & ~(size_t)255; return r; };
  size_t o_xf32 = place((size_t)NP * 128 * 4);
  size_t o_y    = place((size_t)NP * 128 * 2);
  size_t o_g    = place((size_t)NP * 128 * 2);
  size_t o_Am   = place(128 * 128 * 2);
  size_t o_Wb   = place(128 * 128 * 2);
  size_t o_bf   = place(128 * 4);
  size_t o_flag = place(4);
  size_t o_dinv = place((size_t)NP * 4);
  size_t o_deg  = place((size_t)N * 4);
  size_t o_offs = place((size_t)(N + 1) * 4);
  size_t o_cur  = place((size_t)N * 4);
  size_t o_bsum = place((size_t)nb * 4);
  size_t o_csr  = place((size_t)E * 4);
  if (off > ws_size || in_sizes[0] % 128 != 0 || out_size != N * 128 || n_in < 5) {
    // beacon: 0x3F80 shorts read ~1.0 as bf16 AND ~1.0015 as packed f32
    fill_kernel<<<(out_size * 2 + 255) / 256, 256, 0, stream>>>(
        (unsigned short*)d_out, out_size, (unsigned short)0x3F80);
    return;
  }
  char* basep = (char*)d_ws;
  float* xf32 = (float*)(basep + o_xf32);
  unsigned short* y  = (unsigned short*)(basep + o_y);
  unsigned short* g  = (unsigned short*)(basep + o_g);
  unsigned short* Am = (unsigned short*)(basep + o_Am);
  unsigned short* Wb = (unsigned short*)(basep + o_Wb);
  float* bias_f = (float*)(basep + o_bf);
  int* flag   = (int*)(basep + o_flag);
  float* dinv = (float*)(basep + o_dinv);
  int* deg    = (int*)(basep + o_deg);
  int* offs   = (int*)(basep + o_offs);
  int* cursor = (int*)(basep + o_cur);
  int* bsum   = (int*)(basep + o_bsum);
  int* csr    = (int*)(basep + o_csr);

  hipMemsetAsync(deg, 0, (size_t)N * 4, stream);
  detect_kernel<<<1, 256, 0, stream>>>((const unsigned int*)x_in, flag);
  prep_kernel<<<(128 * 128 + 255) / 256, 256, 0, stream>>>(W, Wphi, bias, flag, Am, Wb, bias_f);
  init_x_kernel<<<(NP * 32 + 255) / 256, 256, 0, stream>>>(x_in, flag, xf32, N, NP);
  hist_kernel<<<(E + 255) / 256, 256, 0, stream>>>(dst, deg, E);
  dinv_kernel<<<(NP + 255) / 256, 256, 0, stream>>>(deg, dinv, N, NP);
  scan_bsum_kernel<<<nb, 256, 0, stream>>>(deg, bsum, N);
  scan_partials_kernel<<<1, 64, 0, stream>>>(bsum, nb);
  scan_final_kernel<<<nb, 256, 0, stream>>>(deg, bsum, offs, cursor, N, E);
  scatter_kernel<<<(E + 255) / 256, 256, 0, stream>>>(src, dst, cursor, csr, E);

  const int gblocks = NP / 64;
  for (int t = 0; t < NUM_ITERS; ++t) {
    gemm_kernel<<<gblocks, 256, 0, stream>>>(xf32, Wb, dinv, nullptr, bias_f,
                                             nullptr, y, nullptr, 0, NP);
    agg_kernel<<<(N + 3) / 4, 256, 0, stream>>>(y, offs, csr, dinv, g, N);
    void* outp = (t == NUM_ITERS - 1) ? d_out : nullptr;
    gemm_kernel<<<gblocks, 256, 0, stream>>>(xf32, Am, dinv, g, bias_f, xf32,
                                             outp, flag, 1, N);
  }
}

// Round 4
// 945.895 us; speedup vs baseline: 1.1448x; 1.1448x over previous
//
#include <hip/hip_runtime.h>
#include <hip/hip_bf16.h>
#include <math.h>

#define GAMMA 0.1f
#define EPSILON 0.1f
#define NUM_ITERS 4
#define BSHIFT 9           // bucket covers 512 dst nodes (pow2 -> shift, no div)

typedef __attribute__((ext_vector_type(8))) short short8;   // 8 bf16 bit-patterns
typedef __attribute__((ext_vector_type(4))) float floatx4;

__device__ __forceinline__ float bf2f(unsigned short u) {
  union { unsigned int i; float f; } v; v.i = ((unsigned int)u) << 16; return v.f;
}
__device__ __forceinline__ unsigned short f2bf(float f) {
  union { float f; unsigned int i; } v; v.f = f;
  unsigned int x = v.i;
  return (unsigned short)((x + 0x7fffu + ((x >> 16) & 1u)) >> 16);
}
__device__ __forceinline__ unsigned int f2_to_bfx2(float a, float b) {
  return (unsigned int)f2bf(a) | (((unsigned int)f2bf(b)) << 16);
}
__device__ __forceinline__ float2 bfx2_to_f2(unsigned int u) {
  union { unsigned int i; float f; } lo, hi;
  lo.i = u << 16; hi.i = u & 0xffff0000u;
  return make_float2(lo.f, hi.f);
}

// ------------------------------------------------------------- dtype detect

__global__ void detect_kernel(const unsigned int* __restrict__ x, int* __restrict__ flag) {
  __shared__ int ws4[4];
  int tid = threadIdx.x;
  int bad = 0;
  for (int i = tid; i < 2048; i += 256) {
    unsigned int u = x[i];
    float lo = bf2f((unsigned short)(u & 0xffffu));
    if (!(fabsf(lo) <= 64.0f)) bad++;
  }
#pragma unroll
  for (int d = 1; d < 64; d <<= 1) bad += __shfl_xor(bad, d, 64);
  if ((tid & 63) == 0) ws4[tid >> 6] = bad;
  __syncthreads();
  if (tid == 0) *flag = (ws4[0] + ws4[1] + ws4[2] + ws4[3] > 64) ? 1 : 0;
}

// ------------------------------------------------------------- setup

__global__ void fill_kernel(unsigned short* __restrict__ out, int n, unsigned short val) {
  int t = blockIdx.x * blockDim.x + threadIdx.x;
  if (t < n) out[t] = val;
}

__global__ void prep_kernel(const void* __restrict__ Wv, const void* __restrict__ Wphiv,
                            const void* __restrict__ biasv, const int* __restrict__ flag,
                            unsigned short* __restrict__ Am, unsigned short* __restrict__ Wb,
                            float* __restrict__ bias_f) {
  int t = blockIdx.x * blockDim.x + threadIdx.x;
  if (t >= 128 * 128) return;
  int isf = *flag;
  int j = t >> 7, k = t & 127;
  float w_jk, w_kj, wp;
  if (isf) {
    const float* W = (const float*)Wv;
    const float* Wp = (const float*)Wphiv;
    w_jk = W[t]; w_kj = W[k * 128 + j]; wp = Wp[t];
  } else {
    const unsigned short* W = (const unsigned short*)Wv;
    const unsigned short* Wp = (const unsigned short*)Wphiv;
    w_jk = bf2f(W[t]); w_kj = bf2f(W[k * 128 + j]); wp = bf2f(Wp[t]);
  }
  float v = w_jk - w_kj;
  if (j == k) v -= GAMMA;
  Am[t] = f2bf(v);
  Wb[t] = f2bf(wp);
  if (t < 128)
    bias_f[t] = isf ? ((const float*)biasv)[t] : bf2f(((const unsigned short*)biasv)[t]);
}

__global__ void init_x_kernel(const void* __restrict__ xinv, const int* __restrict__ flag,
                              float* __restrict__ xf32, int N, int NP) {
  int t = blockIdx.x * blockDim.x + threadIdx.x;
  if (t >= NP * 32) return;
  int base = t * 4;
  int row = base >> 7;
  float4 o;
  if (row < N) {
    if (*flag) {
      o = *(const float4*)((const float*)xinv + base);
    } else {
      uint2 v = *(const uint2*)((const unsigned short*)xinv + base);
      float2 f0 = bfx2_to_f2(v.x), f1 = bfx2_to_f2(v.y);
      o = make_float4(f0.x, f0.y, f1.x, f1.y);
    }
  } else {
    o = make_float4(0.f, 0.f, 0.f, 0.f);
  }
  *(float4*)(xf32 + base) = o;
}

// -------------------- bucketed CSR build (no random 4B scatter) --------------

// Phase A: per-block LDS hist of dst>>BSHIFT -> global bucket counts
__global__ void bcount_kernel(const int* __restrict__ dst, int* __restrict__ gcnt,
                              int E, int NB) {
  __shared__ int cnt[512];
  int tid = threadIdx.x;
  for (int j = tid; j < 512; j += 256) cnt[j] = 0;
  __syncthreads();
  int base = blockIdx.x * 4096;
#pragma unroll
  for (int k = 0; k < 16; ++k) {
    int i = base + k * 256 + tid;
    if (i < E) atomicAdd(&cnt[dst[i] >> BSHIFT], 1);
  }
  __syncthreads();
  for (int j = tid; j < NB; j += 256)
    if (cnt[j]) atomicAdd(&gcnt[j], cnt[j]);
}

// serial scan of NB bucket counts -> gofs (+ gcur copy)
__global__ void bscan_kernel(const int* __restrict__ gcnt, int* __restrict__ gofs,
                             int* __restrict__ gcur, int NB, int E) {
  if (threadIdx.x == 0 && blockIdx.x == 0) {
    int run = 0;
    for (int i = 0; i < NB; ++i) { gofs[i] = run; gcur[i] = run; run += gcnt[i]; }
    gofs[NB] = E;
  }
}

// Phase B: per-block reserve per-bucket ranges, write (dst,src) pairs grouped
__global__ void bscatter_kernel(const int* __restrict__ src, const int* __restrict__ dst,
                                int* __restrict__ gcur, uint2* __restrict__ bpairs,
                                int E, int NB) {
  __shared__ int cnt[512];
  __shared__ int pos[512];
  int tid = threadIdx.x;
  for (int j = tid; j < 512; j += 256) cnt[j] = 0;
  __syncthreads();
  int base = blockIdx.x * 4096;
#pragma unroll
  for (int k = 0; k < 16; ++k) {
    int i = base + k * 256 + tid;
    if (i < E) atomicAdd(&cnt[dst[i] >> BSHIFT], 1);
  }
  __syncthreads();
  for (int j = tid; j < NB; j += 256)
    pos[j] = cnt[j] ? atomicAdd(&gcur[j], cnt[j]) : 0;
  __syncthreads();
#pragma unroll
  for (int k = 0; k < 16; ++k) {
    int i = base + k * 256 + tid;
    if (i < E) {
      int d = dst[i];
      int slot = atomicAdd(&pos[d >> BSHIFT], 1);
      bpairs[slot] = make_uint2((unsigned)d, (unsigned)src[i]);
    }
  }
}

// Phase C1: per-bucket degree histogram -> coalesced deg write
__global__ void bdeg_kernel(const uint2* __restrict__ bpairs, const int* __restrict__ gofs,
                            int* __restrict__ deg, int N) {
  __shared__ int dl[512];
  int b = blockIdx.x, tid = threadIdx.x;
  int node0 = b << BSHIFT;
  for (int j = tid; j < 512; j += 256) dl[j] = 0;
  __syncthreads();
  int e0 = gofs[b], e1 = gofs[b + 1];
  for (int i = e0 + tid; i < e1; i += 256)
    atomicAdd(&dl[bpairs[i].x - node0], 1);
  __syncthreads();
  for (int j = tid; j < 512; j += 256) {
    int node = node0 + j;
    if (node < N) deg[node] = dl[j];
  }
}

// Phase C2: per-bucket placement into csr via LDS cursors (writes stay in a
// ~deg*512*4B window owned by this block -> no line amplification)
__global__ void bplace_kernel(const uint2* __restrict__ bpairs, const int* __restrict__ gofs,
                              const int* __restrict__ offs, int* __restrict__ csr, int N) {
  __shared__ int cur[512];
  int b = blockIdx.x, tid = threadIdx.x;
  int node0 = b << BSHIFT;
  for (int j = tid; j < 512; j += 256) {
    int node = node0 + j;
    cur[j] = (node < N) ? offs[node] : 0;
  }
  __syncthreads();
  int e0 = gofs[b], e1 = gofs[b + 1];
  for (int i = e0 + tid; i < e1; i += 256) {
    uint2 p = bpairs[i];
    int s = atomicAdd(&cur[p.x - node0], 1);
    csr[s] = (int)p.y;
  }
}

__global__ void dinv_kernel(const int* __restrict__ deg, float* __restrict__ dinv,
                            int N, int NP) {
  int t = blockIdx.x * blockDim.x + threadIdx.x;
  if (t >= NP) return;
  dinv[t] = (t < N) ? rsqrtf((float)deg[t] + 1.0f) : 1.0f;
}

// -------- 3-kernel exclusive scan of deg -> offs, 1024 elems/block

__global__ void scan_bsum_kernel(const int* __restrict__ counts, int* __restrict__ bsum, int n) {
  __shared__ int wsh[4];
  int tid = threadIdx.x;
  int i0 = blockIdx.x * 1024 + tid * 4;
  int s = 0;
#pragma unroll
  for (int k = 0; k < 4; ++k) { int i = i0 + k; if (i < n) s += counts[i]; }
#pragma unroll
  for (int d = 1; d < 64; d <<= 1) s += __shfl_xor(s, d, 64);
  if ((tid & 63) == 0) wsh[tid >> 6] = s;
  __syncthreads();
  if (tid == 0) bsum[blockIdx.x] = wsh[0] + wsh[1] + wsh[2] + wsh[3];
}

__global__ void scan_partials_kernel(int* __restrict__ bsum, int nb) {
  if (threadIdx.x == 0 && blockIdx.x == 0) {
    int run = 0;
    for (int i = 0; i < nb; ++i) { int v = bsum[i]; bsum[i] = run; run += v; }
  }
}

__global__ void scan_final_kernel(const int* __restrict__ counts, const int* __restrict__ bsum,
                                  int* __restrict__ offs, int n, int total) {
  __shared__ int wsh[4];
  int tid = threadIdx.x, lane = tid & 63, wid = tid >> 6;
  int i0 = blockIdx.x * 1024 + tid * 4;
  int v[4]; int s = 0;
#pragma unroll
  for (int k = 0; k < 4; ++k) { int i = i0 + k; v[k] = (i < n) ? counts[i] : 0; s += v[k]; }
  int incl = s;
#pragma unroll
  for (int d = 1; d < 64; d <<= 1) { int t2 = __shfl_up(incl, d, 64); if (lane >= d) incl += t2; }
  if (lane == 63) wsh[wid] = incl;
  __syncthreads();
  int wexcl = 0;
  for (int k = 0; k < wid; ++k) wexcl += wsh[k];
  int run = bsum[blockIdx.x] + wexcl + (incl - s);
#pragma unroll
  for (int k = 0; k < 4; ++k) {
    int i = i0 + k;
    if (i < n) offs[i] = run;
    run += v[k];
  }
  if (blockIdx.x == 0 && tid == 0) offs[n] = total;
}

// ------------------------------------------------------------- per-iteration

// iter-0 only: y = bf16( (x@Wphi^T) * dinv[row] )
__global__ __launch_bounds__(256) void gemm0_kernel(
    const float* __restrict__ xf32, const unsigned short* __restrict__ Bmat,
    const float* __restrict__ dinv, unsigned short* __restrict__ ybuf) {
  __shared__ unsigned short xs[64 * 128];
  __shared__ unsigned short bs[128 * 128];
  const int tid = threadIdx.x, lane = tid & 63, wid = tid >> 6;
  const int m0 = blockIdx.x * 64;
  {
    int r = tid >> 2, q = tid & 3;
    const float* srcp = xf32 + (size_t)(m0 + r) * 128 + q * 32;
    unsigned short* dstp = xs + r * 128 + q * 32;
#pragma unroll
    for (int k = 0; k < 8; ++k) {
      float4 f = *(const float4*)(srcp + k * 4);
      *(uint2*)(dstp + k * 4) = make_uint2(f2_to_bfx2(f.x, f.y), f2_to_bfx2(f.z, f.w));
    }
  }
  {
    int r = tid >> 1, h = tid & 1;
#pragma unroll
    for (int k = 0; k < 8; ++k)
      *(uint4*)(bs + r * 128 + h * 64 + k * 8) = *(const uint4*)(Bmat + r * 128 + h * 64 + k * 8);
  }
  __syncthreads();
  const int l15 = lane & 15, quad = lane >> 4;
  floatx4 acc[8];
  const floatx4 zero = {0.f, 0.f, 0.f, 0.f};
#pragma unroll
  for (int j = 0; j < 8; ++j) acc[j] = zero;
#pragma unroll
  for (int kk = 0; kk < 4; ++kk) {
    const int koff = kk * 32 + quad * 8;
    short8 a = *(const short8*)&xs[(wid * 16 + l15) * 128 + koff];
#pragma unroll
    for (int j = 0; j < 8; ++j) {
      short8 b = *(const short8*)&bs[(j * 16 + l15) * 128 + koff];
      acc[j] = __builtin_amdgcn_mfma_f32_16x16x32_bf16(a, b, acc[j], 0, 0, 0);
    }
  }
#pragma unroll
  for (int r = 0; r < 4; ++r) {
    int row = m0 + wid * 16 + quad * 4 + r;
    float dv = dinv[row];
#pragma unroll
    for (int j = 0; j < 8; ++j)
      ybuf[(size_t)row * 128 + j * 16 + l15] = f2bf(acc[j][r] * dv);
  }
}

// fused update: s = x@Am^T + g + bias; h=tanh(s); x' = x + eps*h (f32 state);
// optional out write (f32/bf16 per flag); if ybuf: y' = bf16((x'@Wphi^T)*dinv)
__global__ __launch_bounds__(256) void fused_kernel(
    float* __restrict__ xf32, const unsigned short* __restrict__ Am,
    const unsigned short* __restrict__ Wphi, const float* __restrict__ dinv,
    const unsigned short* __restrict__ g, const float* __restrict__ bias_f,
    void* __restrict__ outb, unsigned short* __restrict__ ybuf,
    const int* __restrict__ flag, int Mvalid) {
  __shared__ unsigned short xs[64 * 128];    // 16 KB
  __shared__ unsigned short bs[128 * 128];   // 32 KB (Am, then Wphi)
  const int tid = threadIdx.x, lane = tid & 63, wid = tid >> 6;
  const int m0 = blockIdx.x * 64;

  {
    int r = tid >> 2, q = tid & 3;
    const float* srcp = xf32 + (size_t)(m0 + r) * 128 + q * 32;
    unsigned short* dstp = xs + r * 128 + q * 32;
#pragma unroll
    for (int k = 0; k < 8; ++k) {
      float4 f = *(const float4*)(srcp + k * 4);
      *(uint2*)(dstp + k * 4) = make_uint2(f2_to_bfx2(f.x, f.y), f2_to_bfx2(f.z, f.w));
    }
  }
  {
    int r = tid >> 1, h = tid & 1;
#pragma unroll
    for (int k = 0; k < 8; ++k)
      *(uint4*)(bs + r * 128 + h * 64 + k * 8) = *(const uint4*)(Am + r * 128 + h * 64 + k * 8);
  }
  __syncthreads();

  const int l15 = lane & 15, quad = lane >> 4;
  floatx4 acc[8];
  const floatx4 zero = {0.f, 0.f, 0.f, 0.f};
#pragma unroll
  for (int j = 0; j < 8; ++j) acc[j] = zero;
#pragma unroll
  for (int kk = 0; kk < 4; ++kk) {
    const int koff = kk * 32 + quad * 8;
    short8 a = *(const short8*)&xs[(wid * 16 + l15) * 128 + koff];
#pragma unroll
    for (int j = 0; j < 8; ++j) {
      short8 b = *(const short8*)&bs[(j * 16 + l15) * 128 + koff];
      acc[j] = __builtin_amdgcn_mfma_f32_16x16x32_bf16(a, b, acc[j], 0, 0, 0);
    }
  }

  // epilogue: C/D layout col=lane&15, row=(lane>>4)*4+reg
  float xn[4][8];
  const int isf = *flag;
#pragma unroll
  for (int r = 0; r < 4; ++r) {
    int row = m0 + wid * 16 + quad * 4 + r;
    if (row < Mvalid) {
#pragma unroll
      for (int j = 0; j < 8; ++j) {
        int col = j * 16 + l15;
        size_t idx = (size_t)row * 128 + col;
        float s = acc[j][r] + bf2f(g[idx]) + bias_f[col];
        float h = tanhf(s);
        float x = xf32[idx] + EPSILON * h;
        xf32[idx] = x;
        xn[r][j] = x;
        if (outb) {
          if (isf) ((float*)outb)[idx] = x;
          else     ((unsigned short*)outb)[idx] = f2bf(x);
        }
      }
    }
  }

  if (ybuf) {
    __syncthreads();  // all MFMA1 LDS reads done before overwrite
    // xs <- bf16(x'); pad rows (>=Mvalid) keep old value (0)
#pragma unroll
    for (int r = 0; r < 4; ++r) {
      int row = m0 + wid * 16 + quad * 4 + r;
      if (row < Mvalid) {
        int lrow = wid * 16 + quad * 4 + r;
#pragma unroll
        for (int j = 0; j < 8; ++j)
          xs[lrow * 128 + j * 16 + l15] = f2bf(xn[r][j]);
      }
    }
    // bs <- Wphi
    {
      int r = tid >> 1, h = tid & 1;
#pragma unroll
      for (int k = 0; k < 8; ++k)
        *(uint4*)(bs + r * 128 + h * 64 + k * 8) = *(const uint4*)(Wphi + r * 128 + h * 64 + k * 8);
    }
    __syncthreads();
#pragma unroll
    for (int j = 0; j < 8; ++j) acc[j] = zero;
#pragma unroll
    for (int kk = 0; kk < 4; ++kk) {
      const int koff = kk * 32 + quad * 8;
      short8 a = *(const short8*)&xs[(wid * 16 + l15) * 128 + koff];
#pragma unroll
      for (int j = 0; j < 8; ++j) {
        short8 b = *(const short8*)&bs[(j * 16 + l15) * 128 + koff];
        acc[j] = __builtin_amdgcn_mfma_f32_16x16x32_bf16(a, b, acc[j], 0, 0, 0);
      }
    }
#pragma unroll
    for (int r = 0; r < 4; ++r) {
      int row = m0 + wid * 16 + quad * 4 + r;
      float dv = dinv[row];
#pragma unroll
      for (int j = 0; j < 8; ++j)
        ybuf[(size_t)row * 128 + j * 16 + l15] = f2bf(acc[j][r] * dv);
    }
  }
}

// one wave per node: g[i] = bf16( dinv[i] * ( sum_{e in(i)} y[src_e] + y[i] ) )
__global__ __launch_bounds__(256) void agg_kernel(
    const unsigned short* __restrict__ y,
    const int* __restrict__ offs,
    const int* __restrict__ csr_src,
    const float* __restrict__ dinv,
    unsigned short* __restrict__ g,
    int N) {
  int i = blockIdx.x * 4 + (threadIdx.x >> 6);
  if (i >= N) return;
  int lane = threadIdx.x & 63;
  int c2 = lane * 2;

  float2 acc = bfx2_to_f2(*(const unsigned int*)(y + (size_t)i * 128 + c2));  // self

  int e0 = offs[i], e1 = offs[i + 1];
  int e = e0;
  for (; e + 2 <= e1; e += 2) {
    int s0 = csr_src[e], s1 = csr_src[e + 1];
    float2 f0 = bfx2_to_f2(*(const unsigned int*)(y + (size_t)s0 * 128 + c2));
    float2 f1 = bfx2_to_f2(*(const unsigned int*)(y + (size_t)s1 * 128 + c2));
    acc.x += f0.x + f1.x;
    acc.y += f0.y + f1.y;
  }
  if (e < e1) {
    int s0 = csr_src[e];
    float2 f0 = bfx2_to_f2(*(const unsigned int*)(y + (size_t)s0 * 128 + c2));
    acc.x += f0.x;
    acc.y += f0.y;
  }
  float dv = dinv[i];
  *(unsigned int*)(g + (size_t)i * 128 + c2) = f2_to_bfx2(acc.x * dv, acc.y * dv);
}

// ------------------------------------------------------------- launch

extern "C" void kernel_launch(void* const* d_in, const int* in_sizes, int n_in,
                              void* d_out, int out_size, void* d_ws, size_t ws_size,
                              hipStream_t stream) {
  const void* x_in = d_in[0];
  const int* ei = (const int*)d_in[1];
  const void* W = d_in[2];
  const void* Wphi = d_in[3];
  const void* bias = d_in[4];

  const int N = in_sizes[0] / 128;
  const int E = in_sizes[1] / 2;
  const int NP = ((N + 63) / 64) * 64;
  const int* src = ei;
  const int* dst = ei + E;
  const int nb = (N + 1023) / 1024;
  const int NB = (N + 511) >> BSHIFT;           // buckets of 512 dst nodes
  const int EB = (E + 4095) / 4096;             // edge blocks (4096 edges each)

  size_t off = 0;
  auto place = [&](size_t bytes) { size_t r = off; off = (off + bytes + 255) & ~(size_t)255; return r; };
  size_t o_xf32 = place((size_t)NP * 128 * 4);
  size_t o_y    = place((size_t)NP * 128 * 2);
  size_t o_g    = place((size_t)NP * 128 * 2);
  size_t o_Am   = place(128 * 128 * 2);
  size_t o_Wb   = place(128 * 128 * 2);
  size_t o_bf   = place(128 * 4);
  size_t o_flag = place(4);
  size_t o_dinv = place((size_t)NP * 4);
  size_t o_deg  = place((size_t)N * 4);
  size_t o_offs = place((size_t)(N + 1) * 4);
  size_t o_bsum = place((size_t)nb * 4);
  size_t o_gcnt = place((size_t)NB * 4);
  size_t o_gofs = place((size_t)(NB + 1) * 4);
  size_t o_gcur = place((size_t)NB * 4);
  size_t o_bprs = place((size_t)E * 8);
  size_t o_csr  = place((size_t)E * 4);
  if (off > ws_size || in_sizes[0] % 128 != 0 || out_size != N * 128 || n_in < 5) {
    fill_kernel<<<(out_size * 2 + 255) / 256, 256, 0, stream>>>(
        (unsigned short*)d_out, out_size, (unsigned short)0x3F80);
    return;
  }
  char* basep = (char*)d_ws;
  float* xf32 = (float*)(basep + o_xf32);
  unsigned short* y  = (unsigned short*)(basep + o_y);
  unsigned short* g  = (unsigned short*)(basep + o_g);
  unsigned short* Am = (unsigned short*)(basep + o_Am);
  unsigned short* Wb = (unsigned short*)(basep + o_Wb);
  float* bias_f = (float*)(basep + o_bf);
  int* flag   = (int*)(basep + o_flag);
  float* dinv = (float*)(basep + o_dinv);
  int* deg    = (int*)(basep + o_deg);
  int* offs   = (int*)(basep + o_offs);
  int* bsum   = (int*)(basep + o_bsum);
  int* gcnt   = (int*)(basep + o_gcnt);
  int* gofs   = (int*)(basep + o_gofs);
  int* gcur   = (int*)(basep + o_gcur);
  uint2* bpairs = (uint2*)(basep + o_bprs);
  int* csr    = (int*)(basep + o_csr);

  hipMemsetAsync(gcnt, 0, (size_t)NB * 4, stream);
  detect_kernel<<<1, 256, 0, stream>>>((const unsigned int*)x_in, flag);
  prep_kernel<<<(128 * 128 + 255) / 256, 256, 0, stream>>>(W, Wphi, bias, flag, Am, Wb, bias_f);
  init_x_kernel<<<(NP * 32 + 255) / 256, 256, 0, stream>>>(x_in, flag, xf32, N, NP);
  bcount_kernel<<<EB, 256, 0, stream>>>(dst, gcnt, E, NB);
  bscan_kernel<<<1, 64, 0, stream>>>(gcnt, gofs, gcur, NB, E);
  bscatter_kernel<<<EB, 256, 0, stream>>>(src, dst, gcur, bpairs, E, NB);
  bdeg_kernel<<<NB, 256, 0, stream>>>(bpairs, gofs, deg, N);
  dinv_kernel<<<(NP + 255) / 256, 256, 0, stream>>>(deg, dinv, N, NP);
  scan_bsum_kernel<<<nb, 256, 0, stream>>>(deg, bsum, N);
  scan_partials_kernel<<<1, 64, 0, stream>>>(bsum, nb);
  scan_final_kernel<<<nb, 256, 0, stream>>>(deg, bsum, offs, N, E);
  bplace_kernel<<<NB, 256, 0, stream>>>(bpairs, gofs, offs, csr, N);

  const int gblocks = NP / 64;
  gemm0_kernel<<<gblocks, 256, 0, stream>>>(xf32, Wb, dinv, y);
  for (int t = 0; t < NUM_ITERS; ++t) {
    agg_kernel<<<(N + 3) / 4, 256, 0, stream>>>(y, offs, csr, dinv, g, N);
    void* outp = (t == NUM_ITERS - 1) ? d_out : nullptr;
    unsigned short* ynext = (t == NUM_ITERS - 1) ? nullptr : y;
    fused_kernel<<<gblocks, 256, 0, stream>>>(xf32, Am, Wb, dinv, g, bias_f,
                                              outp, ynext, flag, N);
  }
}

// Round 5
// 788.335 us; speedup vs baseline: 1.3736x; 1.1999x over previous
//
#include <hip/hip_runtime.h>
#include <hip/hip_bf16.h>
#include <math.h>

#define GAMMA 0.1f
#define EPSILON 0.1f
#define NUM_ITERS 4
#define BSHIFT 9           // bucket covers 512 dst nodes

typedef __attribute__((ext_vector_type(8))) short short8;   // 8 bf16 bit-patterns
typedef __attribute__((ext_vector_type(4))) float floatx4;

__device__ __forceinline__ float bf2f(unsigned short u) {
  union { unsigned int i; float f; } v; v.i = ((unsigned int)u) << 16; return v.f;
}
__device__ __forceinline__ unsigned short f2bf(float f) {
  union { float f; unsigned int i; } v; v.f = f;
  unsigned int x = v.i;
  return (unsigned short)((x + 0x7fffu + ((x >> 16) & 1u)) >> 16);
}
__device__ __forceinline__ unsigned int f2_to_bfx2(float a, float b) {
  return (unsigned int)f2bf(a) | (((unsigned int)f2bf(b)) << 16);
}
__device__ __forceinline__ float2 bfx2_to_f2(unsigned int u) {
  union { unsigned int i; float f; } lo, hi;
  lo.i = u << 16; hi.i = u & 0xffff0000u;
  return make_float2(lo.f, hi.f);
}

// ------------------------------------------------------------- dtype detect

__global__ void detect_kernel(const unsigned int* __restrict__ x, int* __restrict__ flag) {
  __shared__ int ws4[4];
  int tid = threadIdx.x;
  int bad = 0;
  for (int i = tid; i < 2048; i += 256) {
    unsigned int u = x[i];
    float lo = bf2f((unsigned short)(u & 0xffffu));
    if (!(fabsf(lo) <= 64.0f)) bad++;
  }
#pragma unroll
  for (int d = 1; d < 64; d <<= 1) bad += __shfl_xor(bad, d, 64);
  if ((tid & 63) == 0) ws4[tid >> 6] = bad;
  __syncthreads();
  if (tid == 0) *flag = (ws4[0] + ws4[1] + ws4[2] + ws4[3] > 64) ? 1 : 0;
}

// ------------------------------------------------------------- setup

__global__ void fill_kernel(unsigned short* __restrict__ out, int n, unsigned short val) {
  int t = blockIdx.x * blockDim.x + threadIdx.x;
  if (t < n) out[t] = val;
}

__global__ void prep_kernel(const void* __restrict__ Wv, const void* __restrict__ Wphiv,
                            const void* __restrict__ biasv, const int* __restrict__ flag,
                            unsigned short* __restrict__ Am, unsigned short* __restrict__ Wb,
                            float* __restrict__ bias_f) {
  int t = blockIdx.x * blockDim.x + threadIdx.x;
  if (t >= 128 * 128) return;
  int isf = *flag;
  int j = t >> 7, k = t & 127;
  float w_jk, w_kj, wp;
  if (isf) {
    const float* W = (const float*)Wv;
    const float* Wp = (const float*)Wphiv;
    w_jk = W[t]; w_kj = W[k * 128 + j]; wp = Wp[t];
  } else {
    const unsigned short* W = (const unsigned short*)Wv;
    const unsigned short* Wp = (const unsigned short*)Wphiv;
    w_jk = bf2f(W[t]); w_kj = bf2f(W[k * 128 + j]); wp = bf2f(Wp[t]);
  }
  float v = w_jk - w_kj;
  if (j == k) v -= GAMMA;
  Am[t] = f2bf(v);
  Wb[t] = f2bf(wp);
  if (t < 128)
    bias_f[t] = isf ? ((const float*)biasv)[t] : bf2f(((const unsigned short*)biasv)[t]);
}

__global__ void init_x_kernel(const void* __restrict__ xinv, const int* __restrict__ flag,
                              float* __restrict__ xf32, int N, int NP) {
  int t = blockIdx.x * blockDim.x + threadIdx.x;
  if (t >= NP * 32) return;
  int base = t * 4;
  int row = base >> 7;
  float4 o;
  if (row < N) {
    if (*flag) {
      o = *(const float4*)((const float*)xinv + base);
    } else {
      uint2 v = *(const uint2*)((const unsigned short*)xinv + base);
      float2 f0 = bfx2_to_f2(v.x), f1 = bfx2_to_f2(v.y);
      o = make_float4(f0.x, f0.y, f1.x, f1.y);
    }
  } else {
    o = make_float4(0.f, 0.f, 0.f, 0.f);
  }
  *(float4*)(xf32 + base) = o;
}

// -------------------- bucketed CSR build (no random 4B scatter) --------------

__global__ void bcount_kernel(const int* __restrict__ dst, int* __restrict__ gcnt,
                              int E, int NB) {
  __shared__ int cnt[512];
  int tid = threadIdx.x;
  for (int j = tid; j < 512; j += 256) cnt[j] = 0;
  __syncthreads();
  int base = blockIdx.x * 4096;
#pragma unroll
  for (int k = 0; k < 16; ++k) {
    int i = base + k * 256 + tid;
    if (i < E) atomicAdd(&cnt[dst[i] >> BSHIFT], 1);
  }
  __syncthreads();
  for (int j = tid; j < NB; j += 256)
    if (cnt[j]) atomicAdd(&gcnt[j], cnt[j]);
}

__global__ void bscan_kernel(const int* __restrict__ gcnt, int* __restrict__ gofs,
                             int* __restrict__ gcur, int NB, int E) {
  if (threadIdx.x == 0 && blockIdx.x == 0) {
    int run = 0;
    for (int i = 0; i < NB; ++i) { gofs[i] = run; gcur[i] = run; run += gcnt[i]; }
    gofs[NB] = E;
  }
}

__global__ void bscatter_kernel(const int* __restrict__ src, const int* __restrict__ dst,
                                int* __restrict__ gcur, uint2* __restrict__ bpairs,
                                int E, int NB) {
  __shared__ int cnt[512];
  __shared__ int pos[512];
  int tid = threadIdx.x;
  for (int j = tid; j < 512; j += 256) cnt[j] = 0;
  __syncthreads();
  int base = blockIdx.x * 4096;
#pragma unroll
  for (int k = 0; k < 16; ++k) {
    int i = base + k * 256 + tid;
    if (i < E) atomicAdd(&cnt[dst[i] >> BSHIFT], 1);
  }
  __syncthreads();
  for (int j = tid; j < NB; j += 256)
    pos[j] = cnt[j] ? atomicAdd(&gcur[j], cnt[j]) : 0;
  __syncthreads();
#pragma unroll
  for (int k = 0; k < 16; ++k) {
    int i = base + k * 256 + tid;
    if (i < E) {
      int d = dst[i];
      int slot = atomicAdd(&pos[d >> BSHIFT], 1);
      bpairs[slot] = make_uint2((unsigned)d, (unsigned)src[i]);
    }
  }
}

// merged finalize: per-bucket degree hist -> LDS scan -> offs/dinv (coalesced)
// -> LDS-cursor placement into csr. Global offs = gofs[b] + local prefix,
// valid because bucket b's edges occupy exactly [gofs[b], gofs[b+1]).
__global__ __launch_bounds__(256) void bfinal_kernel(
    const uint2* __restrict__ bpairs, const int* __restrict__ gofs,
    int* __restrict__ offs, float* __restrict__ dinv, int* __restrict__ csr,
    int N, int NP, int E) {
  __shared__ int dl[512];
  __shared__ int cur[512];
  __shared__ int wsum2[4];
  int b = blockIdx.x, t = threadIdx.x;
  int node0 = b << BSHIFT;
  dl[t] = 0; dl[t + 256] = 0;
  __syncthreads();
  int e0 = gofs[b], e1 = gofs[b + 1];
  for (int i = e0 + t; i < e1; i += 256)
    atomicAdd(&dl[bpairs[i].x - node0], 1);
  __syncthreads();
  int v0 = dl[2 * t], v1 = dl[2 * t + 1];
  int ps = v0 + v1;
  int lane = t & 63, w = t >> 6;
  int inc = ps;
#pragma unroll
  for (int d = 1; d < 64; d <<= 1) { int q = __shfl_up(inc, d, 64); if (lane >= d) inc += q; }
  if (lane == 63) wsum2[w] = inc;
  __syncthreads();
  int woff = 0;
  for (int k = 0; k < w; ++k) woff += wsum2[k];
  int base = e0 + woff + inc - ps;   // global exclusive prefix for node 2t
  int n0 = node0 + 2 * t, n1 = node0 + 2 * t + 1;
  if (n0 < N) offs[n0] = base;
  if (n1 < N) offs[n1] = base + v0;
  if (n0 < NP) dinv[n0] = rsqrtf((float)v0 + 1.0f);
  if (n1 < NP) dinv[n1] = rsqrtf((float)v1 + 1.0f);
  cur[2 * t] = base;
  cur[2 * t + 1] = base + v0;
  if (b == 0 && t == 0) offs[N] = E;
  __syncthreads();
  for (int i = e0 + t; i < e1; i += 256) {
    uint2 p = bpairs[i];
    int s = atomicAdd(&cur[p.x - node0], 1);
    csr[s] = (int)p.y;
  }
}

// ------------------------------------------------------------- per-iteration

// iter-0 only: y = bf16( (x@Wphi^T) * dinv[row] )
__global__ __launch_bounds__(256) void gemm0_kernel(
    const float* __restrict__ xf32, const unsigned short* __restrict__ Bmat,
    const float* __restrict__ dinv, unsigned short* __restrict__ ybuf) {
  __shared__ unsigned short xs[64 * 128];
  __shared__ unsigned short bs[128 * 128];
  const int tid = threadIdx.x, lane = tid & 63, wid = tid >> 6;
  const int m0 = blockIdx.x * 64;
  {
    int r = tid >> 2, q = tid & 3;
    const float* srcp = xf32 + (size_t)(m0 + r) * 128 + q * 32;
    unsigned short* dstp = xs + r * 128 + q * 32;
#pragma unroll
    for (int k = 0; k < 8; ++k) {
      float4 f = *(const float4*)(srcp + k * 4);
      *(uint2*)(dstp + k * 4) = make_uint2(f2_to_bfx2(f.x, f.y), f2_to_bfx2(f.z, f.w));
    }
  }
  {
    int r = tid >> 1, h = tid & 1;
#pragma unroll
    for (int k = 0; k < 8; ++k)
      *(uint4*)(bs + r * 128 + h * 64 + k * 8) = *(const uint4*)(Bmat + r * 128 + h * 64 + k * 8);
  }
  __syncthreads();
  const int l15 = lane & 15, quad = lane >> 4;
  floatx4 acc[8];
  const floatx4 zero = {0.f, 0.f, 0.f, 0.f};
#pragma unroll
  for (int j = 0; j < 8; ++j) acc[j] = zero;
#pragma unroll
  for (int kk = 0; kk < 4; ++kk) {
    const int koff = kk * 32 + quad * 8;
    short8 a = *(const short8*)&xs[(wid * 16 + l15) * 128 + koff];
#pragma unroll
    for (int j = 0; j < 8; ++j) {
      short8 b = *(const short8*)&bs[(j * 16 + l15) * 128 + koff];
      acc[j] = __builtin_amdgcn_mfma_f32_16x16x32_bf16(a, b, acc[j], 0, 0, 0);
    }
  }
#pragma unroll
  for (int r = 0; r < 4; ++r) {
    int row = m0 + wid * 16 + quad * 4 + r;
    float dv = dinv[row];
#pragma unroll
    for (int j = 0; j < 8; ++j)
      ybuf[(size_t)row * 128 + j * 16 + l15] = f2bf(acc[j][r] * dv);
  }
}

// fused update: s = x@Am^T + g + bias; h=tanh(s); x' = x + eps*h (f32 state);
// optional out write (f32/bf16 per flag); if ybuf: y' = bf16((x'@Wphi^T)*dinv)
__global__ __launch_bounds__(256) void fused_kernel(
    float* __restrict__ xf32, const unsigned short* __restrict__ Am,
    const unsigned short* __restrict__ Wphi, const float* __restrict__ dinv,
    const unsigned short* __restrict__ g, const float* __restrict__ bias_f,
    void* __restrict__ outb, unsigned short* __restrict__ ybuf,
    const int* __restrict__ flag, int Mvalid) {
  __shared__ unsigned short xs[64 * 128];    // 16 KB
  __shared__ unsigned short bs[128 * 128];   // 32 KB (Am, then Wphi)
  const int tid = threadIdx.x, lane = tid & 63, wid = tid >> 6;
  const int m0 = blockIdx.x * 64;

  {
    int r = tid >> 2, q = tid & 3;
    const float* srcp = xf32 + (size_t)(m0 + r) * 128 + q * 32;
    unsigned short* dstp = xs + r * 128 + q * 32;
#pragma unroll
    for (int k = 0; k < 8; ++k) {
      float4 f = *(const float4*)(srcp + k * 4);
      *(uint2*)(dstp + k * 4) = make_uint2(f2_to_bfx2(f.x, f.y), f2_to_bfx2(f.z, f.w));
    }
  }
  {
    int r = tid >> 1, h = tid & 1;
#pragma unroll
    for (int k = 0; k < 8; ++k)
      *(uint4*)(bs + r * 128 + h * 64 + k * 8) = *(const uint4*)(Am + r * 128 + h * 64 + k * 8);
  }
  __syncthreads();

  const int l15 = lane & 15, quad = lane >> 4;
  floatx4 acc[8];
  const floatx4 zero = {0.f, 0.f, 0.f, 0.f};
#pragma unroll
  for (int j = 0; j < 8; ++j) acc[j] = zero;
#pragma unroll
  for (int kk = 0; kk < 4; ++kk) {
    const int koff = kk * 32 + quad * 8;
    short8 a = *(const short8*)&xs[(wid * 16 + l15) * 128 + koff];
#pragma unroll
    for (int j = 0; j < 8; ++j) {
      short8 b = *(const short8*)&bs[(j * 16 + l15) * 128 + koff];
      acc[j] = __builtin_amdgcn_mfma_f32_16x16x32_bf16(a, b, acc[j], 0, 0, 0);
    }
  }

  float xn[4][8];
  const int isf = *flag;
#pragma unroll
  for (int r = 0; r < 4; ++r) {
    int row = m0 + wid * 16 + quad * 4 + r;
    if (row < Mvalid) {
#pragma unroll
      for (int j = 0; j < 8; ++j) {
        int col = j * 16 + l15;
        size_t idx = (size_t)row * 128 + col;
        float s = acc[j][r] + bf2f(g[idx]) + bias_f[col];
        float h = tanhf(s);
        float x = xf32[idx] + EPSILON * h;
        xf32[idx] = x;
        xn[r][j] = x;
        if (outb) {
          if (isf) ((float*)outb)[idx] = x;
          else     ((unsigned short*)outb)[idx] = f2bf(x);
        }
      }
    }
  }

  if (ybuf) {
    __syncthreads();
#pragma unroll
    for (int r = 0; r < 4; ++r) {
      int row = m0 + wid * 16 + quad * 4 + r;
      if (row < Mvalid) {
        int lrow = wid * 16 + quad * 4 + r;
#pragma unroll
        for (int j = 0; j < 8; ++j)
          xs[lrow * 128 + j * 16 + l15] = f2bf(xn[r][j]);
      }
    }
    {
      int r = tid >> 1, h = tid & 1;
#pragma unroll
      for (int k = 0; k < 8; ++k)
        *(uint4*)(bs + r * 128 + h * 64 + k * 8) = *(const uint4*)(Wphi + r * 128 + h * 64 + k * 8);
    }
    __syncthreads();
#pragma unroll
    for (int j = 0; j < 8; ++j) acc[j] = zero;
#pragma unroll
    for (int kk = 0; kk < 4; ++kk) {
      const int koff = kk * 32 + quad * 8;
      short8 a = *(const short8*)&xs[(wid * 16 + l15) * 128 + koff];
#pragma unroll
      for (int j = 0; j < 8; ++j) {
        short8 b = *(const short8*)&bs[(j * 16 + l15) * 128 + koff];
        acc[j] = __builtin_amdgcn_mfma_f32_16x16x32_bf16(a, b, acc[j], 0, 0, 0);
      }
    }
#pragma unroll
    for (int r = 0; r < 4; ++r) {
      int row = m0 + wid * 16 + quad * 4 + r;
      float dv = dinv[row];
#pragma unroll
      for (int j = 0; j < 8; ++j)
        ybuf[(size_t)row * 128 + j * 16 + l15] = f2bf(acc[j][r] * dv);
    }
  }
}

// one wave per node, quad-per-edge: 4 edges in flight per load round, unroll 2.
// lane l: quad sub=l>>4 picks the edge, cols (l&15)*8..+8 (uint4 = 8 bf16).
__global__ __launch_bounds__(256) void agg_kernel(
    const unsigned short* __restrict__ y,
    const int* __restrict__ offs,
    const int* __restrict__ csr,
    const float* __restrict__ dinv,
    unsigned short* __restrict__ g,
    int N) {
  int i = blockIdx.x * 4 + (threadIdx.x >> 6);
  if (i >= N) return;
  int lane = threadIdx.x & 63;
  int sub = lane >> 4;
  int c8 = (lane & 15) * 8;

  float a0 = 0.f, a1 = 0.f, a2 = 0.f, a3 = 0.f, a4 = 0.f, a5 = 0.f, a6 = 0.f, a7 = 0.f;

  int e0 = offs[i], e1 = offs[i + 1];
  int e = e0 + sub;
  for (; e + 4 < e1; e += 8) {
    int s0 = csr[e];
    int s1 = csr[e + 4];
    uint4 u0 = *(const uint4*)(y + (size_t)s0 * 128 + c8);
    uint4 u1 = *(const uint4*)(y + (size_t)s1 * 128 + c8);
    float2 f;
    f = bfx2_to_f2(u0.x); a0 += f.x; a1 += f.y;
    f = bfx2_to_f2(u0.y); a2 += f.x; a3 += f.y;
    f = bfx2_to_f2(u0.z); a4 += f.x; a5 += f.y;
    f = bfx2_to_f2(u0.w); a6 += f.x; a7 += f.y;
    f = bfx2_to_f2(u1.x); a0 += f.x; a1 += f.y;
    f = bfx2_to_f2(u1.y); a2 += f.x; a3 += f.y;
    f = bfx2_to_f2(u1.z); a4 += f.x; a5 += f.y;
    f = bfx2_to_f2(u1.w); a6 += f.x; a7 += f.y;
  }
  if (e < e1) {
    int s0 = csr[e];
    uint4 u0 = *(const uint4*)(y + (size_t)s0 * 128 + c8);
    float2 f;
    f = bfx2_to_f2(u0.x); a0 += f.x; a1 += f.y;
    f = bfx2_to_f2(u0.y); a2 += f.x; a3 += f.y;
    f = bfx2_to_f2(u0.z); a4 += f.x; a5 += f.y;
    f = bfx2_to_f2(u0.w); a6 += f.x; a7 += f.y;
  }

  // reduce across the 4 quads (xor 16, 32)
  a0 += __shfl_xor(a0, 16, 64); a0 += __shfl_xor(a0, 32, 64);
  a1 += __shfl_xor(a1, 16, 64); a1 += __shfl_xor(a1, 32, 64);
  a2 += __shfl_xor(a2, 16, 64); a2 += __shfl_xor(a2, 32, 64);
  a3 += __shfl_xor(a3, 16, 64); a3 += __shfl_xor(a3, 32, 64);
  a4 += __shfl_xor(a4, 16, 64); a4 += __shfl_xor(a4, 32, 64);
  a5 += __shfl_xor(a5, 16, 64); a5 += __shfl_xor(a5, 32, 64);
  a6 += __shfl_xor(a6, 16, 64); a6 += __shfl_xor(a6, 32, 64);
  a7 += __shfl_xor(a7, 16, 64); a7 += __shfl_xor(a7, 32, 64);

  if (sub == 0) {
    uint4 su = *(const uint4*)(y + (size_t)i * 128 + c8);
    float2 f;
    f = bfx2_to_f2(su.x); a0 += f.x; a1 += f.y;
    f = bfx2_to_f2(su.y); a2 += f.x; a3 += f.y;
    f = bfx2_to_f2(su.z); a4 += f.x; a5 += f.y;
    f = bfx2_to_f2(su.w); a6 += f.x; a7 += f.y;
    float dv = dinv[i];
    uint4 o;
    o.x = f2_to_bfx2(a0 * dv, a1 * dv);
    o.y = f2_to_bfx2(a2 * dv, a3 * dv);
    o.z = f2_to_bfx2(a4 * dv, a5 * dv);
    o.w = f2_to_bfx2(a6 * dv, a7 * dv);
    *(uint4*)(g + (size_t)i * 128 + c8) = o;
  }
}

// ------------------------------------------------------------- launch

extern "C" void kernel_launch(void* const* d_in, const int* in_sizes, int n_in,
                              void* d_out, int out_size, void* d_ws, size_t ws_size,
                              hipStream_t stream) {
  const void* x_in = d_in[0];
  const int* ei = (const int*)d_in[1];
  const void* W = d_in[2];
  const void* Wphi = d_in[3];
  const void* bias = d_in[4];

  const int N = in_sizes[0] / 128;
  const int E = in_sizes[1] / 2;
  const int NP = ((N + 63) / 64) * 64;
  const int* src = ei;
  const int* dst = ei + E;
  const int NB = (N + 511) >> BSHIFT;
  const int EB = (E + 4095) / 4096;

  size_t off = 0;
  auto place = [&](size_t bytes) { size_t r = off; off = (off + bytes + 255) & ~(size_t)255; return r; };
  size_t o_xf32 = place((size_t)NP * 128 * 4);
  size_t o_y    = place((size_t)NP * 128 * 2);
  size_t o_g    = place((size_t)NP * 128 * 2);
  size_t o_Am   = place(128 * 128 * 2);
  size_t o_Wb   = place(128 * 128 * 2);
  size_t o_bf   = place(128 * 4);
  size_t o_flag = place(4);
  size_t o_dinv = place((size_t)(NB * 512 + 64) * 4);
  size_t o_offs = place((size_t)(N + 1) * 4);
  size_t o_gcnt = place((size_t)NB * 4);
  size_t o_gofs = place((size_t)(NB + 1) * 4);
  size_t o_gcur = place((size_t)NB * 4);
  size_t o_bprs = place((size_t)E * 8);
  size_t o_csr  = place((size_t)E * 4);
  if (off > ws_size || in_sizes[0] % 128 != 0 || out_size != N * 128 || n_in < 5) {
    fill_kernel<<<(out_size * 2 + 255) / 256, 256, 0, stream>>>(
        (unsigned short*)d_out, out_size, (unsigned short)0x3F80);
    return;
  }
  char* basep = (char*)d_ws;
  float* xf32 = (float*)(basep + o_xf32);
  unsigned short* y  = (unsigned short*)(basep + o_y);
  unsigned short* g  = (unsigned short*)(basep + o_g);
  unsigned short* Am = (unsigned short*)(basep + o_Am);
  unsigned short* Wb = (unsigned short*)(basep + o_Wb);
  float* bias_f = (float*)(basep + o_bf);
  int* flag   = (int*)(basep + o_flag);
  float* dinv = (float*)(basep + o_dinv);
  int* offs   = (int*)(basep + o_offs);
  int* gcnt   = (int*)(basep + o_gcnt);
  int* gofs   = (int*)(basep + o_gofs);
  int* gcur   = (int*)(basep + o_gcur);
  uint2* bpairs = (uint2*)(basep + o_bprs);
  int* csr    = (int*)(basep + o_csr);

  hipMemsetAsync(gcnt, 0, (size_t)NB * 4, stream);
  detect_kernel<<<1, 256, 0, stream>>>((const unsigned int*)x_in, flag);
  prep_kernel<<<(128 * 128 + 255) / 256, 256, 0, stream>>>(W, Wphi, bias, flag, Am, Wb, bias_f);
  init_x_kernel<<<(NP * 32 + 255) / 256, 256, 0, stream>>>(x_in, flag, xf32, N, NP);
  bcount_kernel<<<EB, 256, 0, stream>>>(dst, gcnt, E, NB);
  bscan_kernel<<<1, 64, 0, stream>>>(gcnt, gofs, gcur, NB, E);
  bscatter_kernel<<<EB, 256, 0, stream>>>(src, dst, gcur, bpairs, E, NB);
  bfinal_kernel<<<NB, 256, 0, stream>>>(bpairs, gofs, offs, dinv, csr, N, NP, E);

  const int gblocks = NP / 64;
  gemm0_kernel<<<gblocks, 256, 0, stream>>>(xf32, Wb, dinv, y);
  for (int t = 0; t < NUM_ITERS; ++t) {
    agg_kernel<<<(N + 3) / 4, 256, 0, stream>>>(y, offs, csr, dinv, g, N);
    void* outp = (t == NUM_ITERS - 1) ? d_out : nullptr;
    unsigned short* ynext = (t == NUM_ITERS - 1) ? nullptr : y;
    fused_kernel<<<gblocks, 256, 0, stream>>>(xf32, Am, Wb, dinv, g, bias_f,
                                              outp, ynext, flag, N);
  }
}